// Round 1
// baseline (21.638 us; speedup 1.0000x reference)
//
#include <hip/hip_runtime.h>

#define MARGIN 0.15f
#define EPS 1e-8f
#define D 256            // feature dim (fixed by problem: samples are [512, 256] f32)
#define GT 32            // gram tile
#define LDP (D + 4)      // padded LDS row stride (floats), keeps 16B alignment

// ---------------------------------------------------------------------------
// Kernel 1: per-row L2 norm; optionally write normalized rows (Xn) and/or the
// raw norms (rnorm). One wave (64 lanes) per row, float4 per lane (64*4=256).
// ---------------------------------------------------------------------------
__global__ __launch_bounds__(256) void norm_rows(const float* __restrict__ X,
                                                 float* __restrict__ Xn,
                                                 float* __restrict__ rnorm,
                                                 int N) {
    int row = blockIdx.x * 4 + (threadIdx.x >> 6);
    if (row >= N) return;
    int lane = threadIdx.x & 63;
    float4 v = ((const float4*)(X + (size_t)row * D))[lane];
    float ss = v.x * v.x + v.y * v.y + v.z * v.z + v.w * v.w;
#pragma unroll
    for (int off = 32; off; off >>= 1) ss += __shfl_xor(ss, off);
    float nrm = sqrtf(ss);
    if (Xn) {
        float s = nrm > 0.f ? 1.0f / nrm : 0.0f;  // ref eps-clamps denom; norms ~16 here
        float4 o;
        o.x = v.x * s; o.y = v.y * s; o.z = v.z * s; o.w = v.w * s;
        ((float4*)(Xn + (size_t)row * D))[lane] = o;
    }
    if (rnorm && lane == 0) rnorm[row] = nrm;
}

// ---------------------------------------------------------------------------
// Kernel 2: G = Xn * Xn^T  (f32, vector ALU — no fp32 MFMA on CDNA4 and bf16
// would risk accuracy). 32x32 output tile per 256-thread block, 2x2 per
// thread, K staged in LDS, float4 k-loop.
// ---------------------------------------------------------------------------
__global__ __launch_bounds__(256) void gram(const float* __restrict__ Xn,
                                            float* __restrict__ G, int N) {
    __shared__ float As[GT][LDP];
    __shared__ float Bs[GT][LDP];
    int t = threadIdx.x;
    const float4* A4 = (const float4*)(Xn + (size_t)blockIdx.y * GT * D);
    const float4* B4 = (const float4*)(Xn + (size_t)blockIdx.x * GT * D);
#pragma unroll
    for (int i = 0; i < 8; ++i) {
        int f = t + i * 256;          // 0..2047 float4s per tile
        int r = f >> 6, c = f & 63;   // row 0..31, col4 0..63
        float4 a = A4[f];
        *(float4*)&As[r][c * 4] = a;
        float4 b = B4[f];
        *(float4*)&Bs[r][c * 4] = b;
    }
    __syncthreads();
    int tx = t & 15, ty = t >> 4;
    int r0 = ty * 2, c0 = tx * 2;
    float acc00 = 0.f, acc01 = 0.f, acc10 = 0.f, acc11 = 0.f;
#pragma unroll 4
    for (int k = 0; k < D; k += 4) {
        float4 a0 = *(const float4*)&As[r0][k];
        float4 a1 = *(const float4*)&As[r0 + 1][k];
        float4 b0 = *(const float4*)&Bs[c0][k];
        float4 b1 = *(const float4*)&Bs[c0 + 1][k];
        acc00 += a0.x * b0.x + a0.y * b0.y + a0.z * b0.z + a0.w * b0.w;
        acc01 += a0.x * b1.x + a0.y * b1.y + a0.z * b1.z + a0.w * b1.w;
        acc10 += a1.x * b0.x + a1.y * b0.y + a1.z * b0.z + a1.w * b0.w;
        acc11 += a1.x * b1.x + a1.y * b1.y + a1.z * b1.z + a1.w * b1.w;
    }
    size_t orow = (size_t)(blockIdx.y * GT + r0) * N + blockIdx.x * GT + c0;
    float2 o0 = {acc00, acc01};
    float2 o1 = {acc10, acc11};
    *(float2*)&G[orow]     = o0;
    *(float2*)&G[orow + N] = o1;
}

// ---------------------------------------------------------------------------
// Kernel 3a: per-triplet hinge from Gram matrix; deterministic block reduce.
// d_pos - d_neg + m = (1-G[a,p]) - (1-G[a,n]) + m = G[a,n] - G[a,p] + m
// ---------------------------------------------------------------------------
__global__ __launch_bounds__(256) void triplet_g(const float* __restrict__ G,
                                                 const int* __restrict__ ai,
                                                 const int* __restrict__ pi,
                                                 const int* __restrict__ ni,
                                                 float* __restrict__ partial,
                                                 int T, int N) {
    float sum = 0.f;
    for (int t = blockIdx.x * blockDim.x + threadIdx.x; t < T;
         t += gridDim.x * blockDim.x) {
        int a = ai[t], p = pi[t], n = ni[t];
        float gap = G[(size_t)a * N + p];
        float gan = G[(size_t)a * N + n];
        float v = gan - gap + MARGIN;
        sum += v > 0.f ? v : 0.f;
    }
#pragma unroll
    for (int off = 32; off; off >>= 1) sum += __shfl_xor(sum, off);
    __shared__ float red[4];
    int wid = threadIdx.x >> 6;
    if ((threadIdx.x & 63) == 0) red[wid] = sum;
    __syncthreads();
    if (threadIdx.x == 0) partial[blockIdx.x] = red[0] + red[1] + red[2] + red[3];
}

// ---------------------------------------------------------------------------
// Kernel 3b (fallback, small ws): direct per-triplet dots over sample rows.
// ---------------------------------------------------------------------------
__global__ __launch_bounds__(256) void triplet_direct(const float* __restrict__ X,
                                                      const float* __restrict__ rnorm,
                                                      const int* __restrict__ ai,
                                                      const int* __restrict__ pi,
                                                      const int* __restrict__ ni,
                                                      float* __restrict__ partial,
                                                      int T, int N) {
    float sum = 0.f;
    for (int t = blockIdx.x * blockDim.x + threadIdx.x; t < T;
         t += gridDim.x * blockDim.x) {
        int a = ai[t], p = pi[t], n = ni[t];
        const float4* xa = (const float4*)(X + (size_t)a * D);
        const float4* xp = (const float4*)(X + (size_t)p * D);
        const float4* xn = (const float4*)(X + (size_t)n * D);
        float dp = 0.f, dn = 0.f;
#pragma unroll 4
        for (int k = 0; k < D / 4; ++k) {
            float4 av = xa[k], pv = xp[k], nv = xn[k];
            dp += av.x * pv.x + av.y * pv.y + av.z * pv.z + av.w * pv.w;
            dn += av.x * nv.x + av.y * nv.y + av.z * nv.z + av.w * nv.w;
        }
        float na = rnorm[a];
        float denp = fmaxf(na * rnorm[p], EPS);
        float denn = fmaxf(na * rnorm[n], EPS);
        float v = dn / denn - dp / denp + MARGIN;
        sum += v > 0.f ? v : 0.f;
    }
#pragma unroll
    for (int off = 32; off; off >>= 1) sum += __shfl_xor(sum, off);
    __shared__ float red[4];
    int wid = threadIdx.x >> 6;
    if ((threadIdx.x & 63) == 0) red[wid] = sum;
    __syncthreads();
    if (threadIdx.x == 0) partial[blockIdx.x] = red[0] + red[1] + red[2] + red[3];
}

// ---------------------------------------------------------------------------
// Kernel 4: fixed-order final reduce over block partials, scale by 1/T.
// ---------------------------------------------------------------------------
__global__ __launch_bounds__(256) void reduce_partials(const float* __restrict__ partial,
                                                       int nb, float invT,
                                                       float* __restrict__ out) {
    float s = 0.f;
    for (int i = threadIdx.x; i < nb; i += 256) s += partial[i];
#pragma unroll
    for (int off = 32; off; off >>= 1) s += __shfl_xor(s, off);
    __shared__ float red[4];
    int wid = threadIdx.x >> 6;
    if ((threadIdx.x & 63) == 0) red[wid] = s;
    __syncthreads();
    if (threadIdx.x == 0) out[0] = (red[0] + red[1] + red[2] + red[3]) * invT;
}

extern "C" void kernel_launch(void* const* d_in, const int* in_sizes, int n_in,
                              void* d_out, int out_size, void* d_ws, size_t ws_size,
                              hipStream_t stream) {
    const float* X  = (const float*)d_in[0];   // samples [N, D] f32
    const int*   ai = (const int*)d_in[2];     // anchor_idx [T]
    const int*   pi = (const int*)d_in[3];     // pos_idx [T]
    const int*   ni = (const int*)d_in[4];     // neg_idx [T]
    float* out = (float*)d_out;

    int N = in_sizes[1];                       // 512
    int T = in_sizes[2];

    int NB = (T + 255) / 256;
    if (NB > 2048) NB = 2048;
    if (NB < 1) NB = 1;

    size_t xnB   = (size_t)N * D * sizeof(float);
    size_t gB    = (size_t)N * N * sizeof(float);
    size_t partB = 2048 * sizeof(float);

    if (ws_size >= xnB + gB + partB && (N % GT) == 0) {
        // Path A: normalize -> Gram -> triplet hinge -> reduce
        float* Xn      = (float*)d_ws;
        float* G       = (float*)((char*)d_ws + xnB);
        float* partial = (float*)((char*)d_ws + xnB + gB);
        norm_rows<<<(N + 3) / 4, 256, 0, stream>>>(X, Xn, nullptr, N);
        dim3 gg(N / GT, N / GT);
        gram<<<gg, 256, 0, stream>>>(Xn, G, N);
        triplet_g<<<NB, 256, 0, stream>>>(G, ai, pi, ni, partial, T, N);
        reduce_partials<<<1, 256, 0, stream>>>(partial, NB, 1.0f / (float)T, out);
    } else {
        // Path B: norms only + direct per-triplet dot products
        float* rnorm   = (float*)d_ws;
        float* partial = rnorm + N;
        norm_rows<<<(N + 3) / 4, 256, 0, stream>>>(X, nullptr, rnorm, N);
        triplet_direct<<<NB, 256, 0, stream>>>(X, rnorm, ai, pi, ni, partial, T, N);
        reduce_partials<<<1, 256, 0, stream>>>(partial, NB, 1.0f / (float)T, out);
    }
}